// Round 8
// baseline (156.908 us; speedup 1.0000x reference)
//
#include <hip/hip_runtime.h>

#define B_ 2
#define H_ 16
#define S_ 2048
#define D_ 64
#define BQ 128     // q-rows per block: 8 waves = 4 row-groups x 2 key-halves
#define BK 64
#define NQB (S_ / BQ)   // 16 q-blocks per (b,h)
#define NKT (S_ / BK)   // 32 key tiles max
#define LDSH 64    // halfs per LDS row (128B); 16B chunks XOR-swizzled by row&7
#define LOG2E 1.4426950408889634f
#define FIXM 10.0f // fixed softmax shift (log2 domain); cancels exactly in O = PV/l

#if __has_builtin(__builtin_amdgcn_exp2f)
#define EXP2F(x) __builtin_amdgcn_exp2f(x)
#else
#define EXP2F(x) __expf((x) * 0.6931471805599453f)
#endif

typedef _Float16 half8 __attribute__((ext_vector_type(8)));
typedef _Float16 half4 __attribute__((ext_vector_type(4)));
typedef __fp16   fp16x2 __attribute__((ext_vector_type(2)));  // cvt_pkrtz return type
typedef float floatx4 __attribute__((ext_vector_type(4)));

// LDS carve (bytes): KL [2][64][64]h @0 (16K), VT [2][64][64]h @16K (16K),
// lut[256]f @32768. 34304 total -> 3 blocks/CU at grid 768 (103KB of 160KB).
// Epilogue reuses [0,34304) as fp32 scratch: Ox[128][66] @0, Lx[128] @33792.
#define VT_OFF  16384
#define LUT_OFF 32768
#define OX_STR  66
#define LX_OFF  33792
#define SMEM_BYTES 34304

// ---- workspace: 512 partial slots (long batch, 2 per (h,qblk)); same bound
// as round-3's split kernel, which the harness satisfied (split path ran).
#define SLOT_F  8320                       // floats/slot: 8192 O + 128 l
#define WS_NEED (1024u + 512u * SLOT_F * 4u)

// ===========================================================================
// Attention kernel. SPLIT=false: 512 blocks, every block full-range direct
// write (the verified r5 kernel). SPLIT=true: 768 blocks; f<256 -> shorter
// batch full-range direct; f>=256 -> longer batch, key-tile range halved per
// (h,qblk), additive unnormalized partial (O,l) to ws (fixed-shift softmax:
// partials just add). No atomics, no fences: the combine kernel below is
// stream-ordered behind this one.
// ===========================================================================
template <bool SPLIT>
__global__ __launch_bounds__(512, 4)
void t5_attn(const float* __restrict__ qg_, const float* __restrict__ kg_,
             const float* __restrict__ vg_, const float* __restrict__ bt,
             const int* __restrict__ elen, float* __restrict__ outg_,
             float* __restrict__ ws)
{
    __shared__ __align__(16) unsigned char smem[SMEM_BYTES];
    _Float16* KL = reinterpret_cast<_Float16*>(smem);            // [2][4096]
    _Float16* VT = reinterpret_cast<_Float16*>(smem + VT_OFF);   // [2][4096]
    float*   lut = reinterpret_cast<float*>(smem + LUT_OFF);     // [256]

    const int tid  = threadIdx.x;
    const int wave = tid >> 6;
    const int lane = tid & 63;
    const int quad = lane >> 4;
    const int t16  = lane & 15;
    const int t8   = t16 & 15 & 7;   // row parity for the chunk XOR swizzle
    const int wq   = wave >> 1;  // 0..3: q row-group (32 rows)
    const int kh   = wave & 1;   // 0/1: key half (32 keys) of each 64-key tile

    // ---- block role decode. Both modes keep f%8 = h_low (XCD L2 affinity).
    int b, h, qblk, kt0, kt1, len;
    bool partial = false;
    int slotidx = 0;
    if constexpr (!SPLIT) {
        const int f = blockIdx.x + NQB * (blockIdx.y + H_ * blockIdx.z);
        qblk = (f >> 3) & 15;
        const int bh = (f & 7) | ((f >> 7) << 3);
        h = bh & 15;
        b = bh >> 4;
        len = (elen[1] == 0) ? elen[2 * b] : elen[b];   // int32/int64 robust
        kt0 = 0;
        kt1 = (len + 63) >> 6;
    } else {
        const int f = blockIdx.x;            // 0..767
        const int p = f & 255;
        h    = (p & 7) | (((p >> 7) & 1) << 3);
        qblk = (p >> 3) & 15;
        const int l0 = elen[0];
        const int l1 = (elen[1] == 0) ? elen[2] : elen[1];
        const int lb_ = (l1 >= l0) ? 1 : 0;  // longer batch (tie -> 1)
        if (f < 256) {                       // shorter batch, full range
            b   = 1 - lb_;
            len = lb_ ? l0 : l1;
            kt0 = 0;
            kt1 = (len + 63) >> 6;
        } else {                             // longer batch, half range
            b   = lb_;
            len = lb_ ? l1 : l0;
            const int nt   = (len + 63) >> 6;
            const int hh   = (nt + 1) >> 1;
            const int part = (f >> 9) & 1;   // 256..511 -> 0, 512..767 -> 1
            kt0 = part ? hh : 0;
            kt1 = part ? nt : hh;
            partial = true;
            slotidx = p * 2 + part;
        }
    }
    const int ntb = (len + 63) >> 6;         // batch's boundary tile index + 1

    // ---- bias LUT with FIXM folded in: lut[n] = bt[bucket(n)][h]*log2e - FIXM
    if (tid < 256) {
        int n = tid;
        int bucket;
        if (n < 16) {
            bucket = n;
        } else {
            int vl = (int)(__log2f((float)n * 0.0625f) * 4.0f);
            bucket = 16 + (vl < 15 ? vl : 15);
        }
        lut[n] = bt[bucket * H_ + h] * LOG2E - FIXM;
    }
    const float sh_next = FIXM - bt[h] * LOG2E;           // all d<=0 (bucket 0)
    const float sh_far  = FIXM - bt[31 * H_ + h] * LOG2E; // all d>=216 (bucket 31)

    const size_t bhoff = ((size_t)b * H_ + h) * (size_t)(S_ * D_);
    const float* qptr = qg_ + bhoff;
    const float* kptr = kg_ + bhoff;
    const float* vptr = vg_ + bhoff;
    float*       optr = outg_ + bhoff;

    // ---- Q fragments (A-layout used in B slot -> S^T = K.Q^T)
    half8 qf[2][2];
    {
        const float qscale = 0.125f * LOG2E;
        #pragma unroll
        for (int rg = 0; rg < 2; ++rg) {
            const int row = qblk * BQ + wq * 32 + rg * 16 + t16;
            const float* qp = qptr + (size_t)row * D_ + quad * 8;
            #pragma unroll
            for (int c = 0; c < 2; ++c) {
                const float4* pq = reinterpret_cast<const float4*>(qp + c * 32);
                float4 x0 = pq[0], x1 = pq[1];
                half8 hv;
                hv[0] = (_Float16)(x0.x * qscale); hv[1] = (_Float16)(x0.y * qscale);
                hv[2] = (_Float16)(x0.z * qscale); hv[3] = (_Float16)(x0.w * qscale);
                hv[4] = (_Float16)(x1.x * qscale); hv[5] = (_Float16)(x1.y * qscale);
                hv[6] = (_Float16)(x1.z * qscale); hv[7] = (_Float16)(x1.w * qscale);
                qf[rg][c] = hv;
            }
        }
    }

    floatx4 acc[2][4];         // acc[rg][nb][r]: qrow rg*16+quad*4+r, dim nb*16+t16
    float l_[2];               // per-lane partial row-sum (this wave's key-half)
    #pragma unroll
    for (int rg = 0; rg < 2; ++rg) {
        #pragma unroll
        for (int nb = 0; nb < 4; ++nb) acc[rg][nb] = floatx4{0.f, 0.f, 0.f, 0.f};
        l_[rg] = 0.f;
    }

    const int i_lo = qblk * BQ + wq * 32;  // first q-row this wave owns

    auto pack4 = [](const floatx4& v) -> half4 {   // 4 f32 -> half4 (RTZ)
        fp16x2 lo = __builtin_amdgcn_cvt_pkrtz(v[0], v[1]);
        fp16x2 hi = __builtin_amdgcn_cvt_pkrtz(v[2], v[3]);
        half4 w;
        w[0] = (_Float16)lo[0]; w[1] = (_Float16)lo[1];
        w[2] = (_Float16)hi[0]; w[3] = (_Float16)hi[1];
        return w;
    };

    // ---- staging geometry (tile-invariant); one staging register set
    const int krow = tid >> 3;                                       // K row staged
    const int kst  = krow * LDSH + (((tid & 7) ^ (krow & 7)) << 3);  // swizzled
    const int vst  = lane * LDSH + ((wave ^ (lane & 7)) << 3);       // swizzled
    const int c8w  = (tid & 7) << 3;

    float4 kx0, kx1;
    float  vx[8];
    auto prefetch = [&](int kt) {   // tile kt -> regs (clamped for safety)
        const int ktc = kt < NKT ? kt : NKT - 1;
        const float4* pp = reinterpret_cast<const float4*>(
            kptr + (size_t)(ktc * BK + krow) * D_ + c8w);
        kx0 = pp[0];
        kx1 = pp[1];
        const float* vb = vptr + (size_t)(ktc * BK + wave * 8) * D_ + lane;
        #pragma unroll
        for (int jj = 0; jj < 8; ++jj)
            vx[jj] = vb[jj * D_];
    };
    auto stage = [&](int bufe) {    // regs -> LDS buffer (element base bufe)
        half8 hv;
        hv[0]=(_Float16)kx0.x; hv[1]=(_Float16)kx0.y; hv[2]=(_Float16)kx0.z; hv[3]=(_Float16)kx0.w;
        hv[4]=(_Float16)kx1.x; hv[5]=(_Float16)kx1.y; hv[6]=(_Float16)kx1.z; hv[7]=(_Float16)kx1.w;
        *reinterpret_cast<half8*>(KL + bufe + kst) = hv;
        half8 vv;
        #pragma unroll
        for (int jj = 0; jj < 8; ++jj) vv[jj] = (_Float16)vx[jj];
        *reinterpret_cast<half8*>(VT + bufe + vst) = vv;
    };

    if (kt0 < kt1) {
        prefetch(kt0);
        stage(0);
        __syncthreads();

        for (int kt = kt0; kt < kt1; ++kt) {
            const int cur  = (kt - kt0) & 1;
            const int curb = cur * 4096;
            const bool more = (kt + 1) < kt1;
            if (more) prefetch(kt + 1);  // global->regs, hides under compute

            const int keybase = kt * BK + kh * 32;  // this wave's 32 keys

            // wave-uniform bias classification: fold uniform shift into C-init
            const bool unif_next = (i_lo + 31 <= keybase);   // all d<=0 -> bucket 0
            const bool unif_far  = (i_lo >= keybase + 247);  // all d>=216 -> bucket 31
            const float cinit = unif_next ? -sh_next : (unif_far ? -sh_far : 0.f);
            const floatx4 ci = {cinit, cinit, cinit, cinit};

            // ---- S^T = K (Q*log2e/8)^T : row=key (quad*4+r), col=qrow (t16)
            floatx4 sa[2][2];
            #pragma unroll
            for (int rg = 0; rg < 2; ++rg)
                #pragma unroll
                for (int nb = 0; nb < 2; ++nb) sa[rg][nb] = ci;
            __builtin_amdgcn_s_setprio(1);
            #pragma unroll
            for (int kc = 0; kc < 2; ++kc) {
                #pragma unroll
                for (int nb = 0; nb < 2; ++nb) {
                    half8 af = *reinterpret_cast<const half8*>(
                        KL + curb + (kh * 32 + nb * 16 + t16) * LDSH +
                        ((((kc << 2) | quad) ^ t8) << 3));
                    sa[0][nb] = __builtin_amdgcn_mfma_f32_16x16x32_f16(af, qf[0][kc], sa[0][nb], 0, 0, 0);
                    sa[1][nb] = __builtin_amdgcn_mfma_f32_16x16x32_f16(af, qf[1][kc], sa[1][nb], 0, 0, 0);
                }
            }
            __builtin_amdgcn_s_setprio(0);

            // V reads now: independent of sa, latency hides under exp2
            half4 bvv[4][2];
            #pragma unroll
            for (int nb = 0; nb < 4; ++nb) {
                #pragma unroll
                for (int s = 0; s < 2; ++s) {
                    bvv[nb][s] = *reinterpret_cast<const half4*>(
                        VT + curb + (nb * 16 + t16) * LDSH +
                        ((((kh << 2) | (s << 1) | (quad >> 1)) ^ t8) << 3) +
                        ((quad & 1) << 2));
                }
            }

            // LUT bias only on the (few) diagonal tiles
            if (!unif_next && !unif_far) {
                #pragma unroll
                for (int rg = 0; rg < 2; ++rg) {
                    const int d0 = i_lo + rg * 16 + t16 - keybase - quad * 4;
                    #pragma unroll
                    for (int nb = 0; nb < 2; ++nb) {
                        #pragma unroll
                        for (int r = 0; r < 4; ++r) {
                            int d = d0 - nb * 16 - r;
                            d = d < 0 ? 0 : (d > 255 ? 255 : d);
                            sa[rg][nb][r] += lut[d];
                        }
                    }
                }
            }
            // key-padding mask on the batch's boundary tile only
            if ((kt == ntb - 1) && (len & 63)) {
                #pragma unroll
                for (int nb = 0; nb < 2; ++nb) {
                    #pragma unroll
                    for (int r = 0; r < 4; ++r) {
                        bool valid = (keybase + nb * 16 + quad * 4 + r) < len;
                        #pragma unroll
                        for (int rg = 0; rg < 2; ++rg)
                            sa[rg][nb][r] = valid ? sa[rg][nb][r] : -1e30f;
                    }
                }
            }

            // fixed-shift softmax + partial l
            #pragma unroll
            for (int rg = 0; rg < 2; ++rg) {
                float ssum = 0.f;
                #pragma unroll
                for (int nb = 0; nb < 2; ++nb)
                    #pragma unroll
                    for (int r = 0; r < 4; ++r) {
                        sa[rg][nb][r] = EXP2F(sa[rg][nb][r]);
                        ssum += sa[rg][nb][r];
                    }
                l_[rg] += ssum;
            }

            // O += P V, P in registers (16x16x16: A-operand = S^T C-layout)
            {
                half4 aA0 = pack4(sa[0][0]);
                half4 aB0 = pack4(sa[0][1]);
                half4 aA1 = pack4(sa[1][0]);
                half4 aB1 = pack4(sa[1][1]);
                __builtin_amdgcn_s_setprio(1);
                #pragma unroll
                for (int nb = 0; nb < 4; ++nb) {
                    acc[0][nb] = __builtin_amdgcn_mfma_f32_16x16x16f16(aA0, bvv[nb][0], acc[0][nb], 0, 0, 0);
                    acc[0][nb] = __builtin_amdgcn_mfma_f32_16x16x16f16(aB0, bvv[nb][1], acc[0][nb], 0, 0, 0);
                    acc[1][nb] = __builtin_amdgcn_mfma_f32_16x16x16f16(aA1, bvv[nb][0], acc[1][nb], 0, 0, 0);
                    acc[1][nb] = __builtin_amdgcn_mfma_f32_16x16x16f16(aB1, bvv[nb][1], acc[1][nb], 0, 0, 0);
                }
                __builtin_amdgcn_s_setprio(0);
            }

            if (more) stage((cur ^ 1) * 4096);
            __syncthreads();
        }
    } else {
        __syncthreads();   // empty range (split with nt==1): keep block converged
    }

    // ---- epilogue: kh-combine in LDS (additive; fixed-shift softmax), then
    // direct normalize+store (full-range) or unnormalized partial to ws.
    float lh[2];
    #pragma unroll
    for (int rg = 0; rg < 2; ++rg) {
        float lv = l_[rg];
        lv += __shfl_xor(lv, 16, 64);
        lv += __shfl_xor(lv, 32, 64);
        lh[rg] = lv;  // row-sum over this wave's keys, replicated across quads
    }
    float* Ox = reinterpret_cast<float*>(smem);           // [128][OX_STR]
    float* Lx = reinterpret_cast<float*>(smem + LX_OFF);  // [128]
    if (kh == 1) {
        #pragma unroll
        for (int rg = 0; rg < 2; ++rg) {
            #pragma unroll
            for (int nb = 0; nb < 4; ++nb)
                #pragma unroll
                for (int r = 0; r < 4; ++r)
                    Ox[(wq * 32 + rg * 16 + quad * 4 + r) * OX_STR + nb * 16 + t16] =
                        acc[rg][nb][r];
            if (quad == 0) Lx[wq * 32 + rg * 16 + t16] = lh[rg];
        }
    }
    __syncthreads();
    if (!partial) {
        if (kh == 0) {
            #pragma unroll
            for (int rg = 0; rg < 2; ++rg) {
                const float inv = 1.f / (lh[rg] + Lx[wq * 32 + rg * 16 + t16]);
                #pragma unroll
                for (int r = 0; r < 4; ++r) {
                    const int rowloc = quad * 4 + r;
                    const float invr = __shfl(inv, (lane & 48) | rowloc, 64);
                    const int row = qblk * BQ + wq * 32 + rg * 16 + rowloc;
                    #pragma unroll
                    for (int nb = 0; nb < 4; ++nb)
                        optr[(size_t)row * D_ + nb * 16 + t16] =
                            (acc[rg][nb][r] +
                             Ox[(wq * 32 + rg * 16 + rowloc) * OX_STR + nb * 16 + t16]) * invr;
                }
            }
        }
    } else {
        float* slot = ws + 256 + (size_t)slotidx * SLOT_F;
        if (kh == 0) {
            #pragma unroll
            for (int rg = 0; rg < 2; ++rg) {
                #pragma unroll
                for (int r = 0; r < 4; ++r) {
                    const int rloc = wq * 32 + rg * 16 + quad * 4 + r;
                    #pragma unroll
                    for (int nb = 0; nb < 4; ++nb)
                        slot[rloc * D_ + nb * 16 + t16] =
                            acc[rg][nb][r] + Ox[rloc * OX_STR + nb * 16 + t16];
                }
                if (quad == 0)
                    slot[8192 + wq * 32 + rg * 16 + t16] =
                        lh[rg] + Lx[wq * 32 + rg * 16 + t16];
            }
        }
    }
}

// ===========================================================================
// Combine: one block per (h,qblk) of the longer batch. Stream-ordered after
// t5_attn<true>; visibility across dispatches is guaranteed by HIP.
// ===========================================================================
__global__ __launch_bounds__(256)
void t5_combine(const int* __restrict__ elen, const float* __restrict__ ws,
                float* __restrict__ outg_)
{
    const int l0 = elen[0];
    const int l1 = (elen[1] == 0) ? elen[2] : elen[1];
    const int lb_ = (l1 >= l0) ? 1 : 0;

    const int p    = blockIdx.x;     // 0..255
    const int h    = (p & 7) | (((p >> 7) & 1) << 3);
    const int qblk = (p >> 3) & 15;

    const float* sA = ws + 256 + (size_t)(p * 2 + 0) * SLOT_F;
    const float* sB = ws + 256 + (size_t)(p * 2 + 1) * SLOT_F;

    const int row = threadIdx.x >> 1;          // 0..127
    const int c32 = (threadIdx.x & 1) << 5;    // 0 or 32

    const float inv = 1.f / (sA[8192 + row] + sB[8192 + row]);
    const float* a  = sA + row * D_ + c32;
    const float* bq = sB + row * D_ + c32;
    float* od = outg_ + (((size_t)lb_ * H_ + h) * S_ + qblk * BQ + row) * D_ + c32;
    #pragma unroll
    for (int j = 0; j < 8; ++j) {
        float4 x = *reinterpret_cast<const float4*>(a + j * 4);
        float4 y = *reinterpret_cast<const float4*>(bq + j * 4);
        float4 o;
        o.x = (x.x + y.x) * inv; o.y = (x.y + y.y) * inv;
        o.z = (x.z + y.z) * inv; o.w = (x.w + y.w) * inv;
        *reinterpret_cast<float4*>(od + j * 4) = o;
    }
}

extern "C" void kernel_launch(void* const* d_in, const int* in_sizes, int n_in,
                              void* d_out, int out_size, void* d_ws, size_t ws_size,
                              hipStream_t stream) {
    const float* q  = (const float*)d_in[0];
    const float* k  = (const float*)d_in[1];
    const float* v  = (const float*)d_in[2];
    const float* bt = (const float*)d_in[3];
    const int*   el = (const int*)d_in[4];
    float* out = (float*)d_out;
    if (d_ws != nullptr && ws_size >= (size_t)WS_NEED) {
        t5_attn<true><<<dim3(768), 512, 0, stream>>>(q, k, v, bt, el, out,
                                                     (float*)d_ws);
        t5_combine<<<dim3(256), 256, 0, stream>>>(el, (const float*)d_ws, out);
    } else {
        t5_attn<false><<<dim3(NQB, H_, B_), 512, 0, stream>>>(q, k, v, bt, el,
                                                              out, nullptr);
    }
}

// Round 10
// 123.959 us; speedup vs baseline: 1.2658x; 1.2658x over previous
//
#include <hip/hip_runtime.h>

#define B_ 2
#define H_ 16
#define S_ 2048
#define D_ 64
#define BQ 128     // q-rows per block: 8 waves = 4 row-groups x 2 key-halves
#define BK 64
#define NQB (S_ / BQ)   // 16 q-blocks per (b,h)
#define NKT (S_ / BK)   // 32 key tiles max
#define LDSH 64    // halfs per LDS row (128B), linear (gload_lds writes linearly)
#define LOG2E 1.4426950408889634f
#define FIXM 10.0f // fixed softmax shift (log2 domain); cancels exactly in O = PV/l

#if __has_builtin(__builtin_amdgcn_exp2f)
#define EXP2F(x) __builtin_amdgcn_exp2f(x)
#else
#define EXP2F(x) __expf((x) * 0.6931471805599453f)
#endif

#if __has_builtin(__builtin_amdgcn_global_load_lds)
#define HAS_GLDS 1
#else
#define HAS_GLDS 0
#endif

typedef _Float16 half8 __attribute__((ext_vector_type(8)));
typedef _Float16 half4 __attribute__((ext_vector_type(4)));
typedef __fp16   fp16x2 __attribute__((ext_vector_type(2)));  // cvt_pkrtz return type
typedef float floatx4 __attribute__((ext_vector_type(4)));

// LDS carve (bytes): KL [2][4096]h @0 (16K), VT [2][4096]h @16K (16K),
// lut[256]f @32768. 34304 total -> 2 blocks/CU.
// Epilogue reuses [0,34304) as fp32 scratch: Ox[128][66] @0, Lx[128] @33792.
#define VT_OFF  16384
#define LUT_OFF 32768
#define OX_STR  66
#define LX_OFF  33792
#define SMEM_BYTES 34304

// ---- workspace: fp16 K (same layout) + fp16 V transposed [d][S], both batches.
// 2 * (2*16*2048*64) * 2B = 16,777,216 B  (< the r3/r8-proven ws bound).
#define KV_ELEMS (B_ * H_ * S_ * D_)             // 4,194,304 per tensor
#define WS_NEED  ((size_t)KV_ELEMS * 2 * 2)      // 16 MB

// ===========================================================================
// Pre-pass: K fp32->fp16 (same layout); V fp32->fp16 TRANSPOSED per (b,h)
// ([S][D] -> [D][S]) via LDS tiles. Memory-bound, ~48 MB traffic.
// ===========================================================================
__global__ __launch_bounds__(256)
void t5_prep(const float* __restrict__ kg_, const float* __restrict__ vg_,
             _Float16* __restrict__ kws, _Float16* __restrict__ vws)
{
    const int t = threadIdx.x;
    if (blockIdx.x < 1024) {
        // K convert: 1024 blocks x 256 thr x 4 float4 (coalesced both ways)
        const float4* src = reinterpret_cast<const float4*>(kg_);
        half4* dst = reinterpret_cast<half4*>(kws);
        #pragma unroll
        for (int it = 0; it < 4; ++it) {
            const size_t i = (size_t)blockIdx.x * 1024 + it * 256 + t;
            float4 x = src[i];
            half4 hv;
            hv[0] = (_Float16)x.x; hv[1] = (_Float16)x.y;
            hv[2] = (_Float16)x.z; hv[3] = (_Float16)x.w;
            dst[i] = hv;
        }
    } else {
        // V transpose: one 64x64 tile per block. tt = bh*32 + kt.
        __shared__ float vt[64][65];
        const int tt = blockIdx.x - 1024;
        const int bh = tt >> 5;          // 0..31
        const int kt = tt & 31;          // 0..31
        const float* vsrc = vg_ + (size_t)bh * (S_ * D_) + (size_t)kt * 64 * D_;
        #pragma unroll
        for (int it = 0; it < 4; ++it) {
            const int idx = it * 256 + t;        // float4 index in tile
            const int key = idx >> 4;
            const int c4  = (idx & 15) << 2;
            float4 x = *reinterpret_cast<const float4*>(vsrc + key * D_ + c4);
            vt[key][c4 + 0] = x.x; vt[key][c4 + 1] = x.y;
            vt[key][c4 + 2] = x.z; vt[key][c4 + 3] = x.w;
        }
        __syncthreads();
        const int d  = t >> 2;               // 0..63 output row (dim)
        const int kq = (t & 3) << 4;         // 16-key chunk
        half8 o0, o1;
        #pragma unroll
        for (int j = 0; j < 8; ++j) {
            o0[j] = (_Float16)vt[kq + j][d];
            o1[j] = (_Float16)vt[kq + 8 + j][d];
        }
        _Float16* dst = vws + (size_t)bh * (D_ * S_) + (size_t)d * S_ + kt * 64 + kq;
        *reinterpret_cast<half8*>(dst)     = o0;
        *reinterpret_cast<half8*>(dst + 8) = o1;
    }
}

#if HAS_GLDS
// ===========================================================================
// Main kernel, gload_lds staging: per wave per tile exactly 2 async
// global_load_lds_dwordx4 issues (K 1KB slice + V 1KB slice). No staging
// VALU, no scalar V loads, no ds_writes. One barrier per tile.
// ===========================================================================
__global__ __launch_bounds__(512, 4)
void t5_attn_g(const float* __restrict__ qg_, const _Float16* __restrict__ kws,
               const _Float16* __restrict__ vws, const float* __restrict__ bt,
               const int* __restrict__ elen, float* __restrict__ outg_)
{
    __shared__ __align__(16) unsigned char smem[SMEM_BYTES];
    _Float16* KL = reinterpret_cast<_Float16*>(smem);            // [2][4096]
    _Float16* VT = reinterpret_cast<_Float16*>(smem + VT_OFF);   // [2][4096]
    float*   lut = reinterpret_cast<float*>(smem + LUT_OFF);     // [256]

    const int tid  = threadIdx.x;
    const int wave = tid >> 6;
    const int lane = tid & 63;
    const int quad = lane >> 4;
    const int t16  = lane & 15;
    const int wq   = wave >> 1;  // 0..3: q row-group (32 rows)
    const int kh   = wave & 1;   // 0/1: key half (32 keys) of each 64-key tile

    // XCD-aware remap (verified FETCH 100->20MB)
    const int f    = blockIdx.x + NQB * (blockIdx.y + H_ * blockIdx.z);
    const int qblk = (f >> 3) & 15;
    const int bh   = (f & 7) | ((f >> 7) << 3);
    const int h    = bh & 15;
    const int b    = bh >> 4;

    // ---- bias LUT with FIXM folded in
    if (tid < 256) {
        int n = tid;
        int bucket;
        if (n < 16) {
            bucket = n;
        } else {
            int vl = (int)(__log2f((float)n * 0.0625f) * 4.0f);
            bucket = 16 + (vl < 15 ? vl : 15);
        }
        lut[n] = bt[bucket * H_ + h] * LOG2E - FIXM;
    }
    const float sh_next = FIXM - bt[h] * LOG2E;           // all d<=0 (bucket 0)
    const float sh_far  = FIXM - bt[31 * H_ + h] * LOG2E; // all d>=216 (bucket 31)

    const int len = (elen[1] == 0) ? elen[2 * b] : elen[b];
    const int ntiles = (len + BK - 1) >> 6;

    const size_t bho = ((size_t)b * H_ + h) * (size_t)(S_ * D_);
    const float* qptr = qg_ + bho;
    float*       optr = outg_ + bho;
    const _Float16* kbh = kws + bho;                         // [2048][64] fp16
    const _Float16* vbh = vws + ((size_t)b * H_ + h) * (size_t)(D_ * S_); // [64][2048]

    // ---- Q fragments (A-layout used in B slot -> S^T = K.Q^T)
    half8 qf[2][2];
    {
        const float qscale = 0.125f * LOG2E;
        #pragma unroll
        for (int rg = 0; rg < 2; ++rg) {
            const int row = qblk * BQ + wq * 32 + rg * 16 + t16;
            const float* qp = qptr + (size_t)row * D_ + quad * 8;
            #pragma unroll
            for (int c = 0; c < 2; ++c) {
                const float4* pq = reinterpret_cast<const float4*>(qp + c * 32);
                float4 x0 = pq[0], x1 = pq[1];
                half8 hv;
                hv[0] = (_Float16)(x0.x * qscale); hv[1] = (_Float16)(x0.y * qscale);
                hv[2] = (_Float16)(x0.z * qscale); hv[3] = (_Float16)(x0.w * qscale);
                hv[4] = (_Float16)(x1.x * qscale); hv[5] = (_Float16)(x1.y * qscale);
                hv[6] = (_Float16)(x1.z * qscale); hv[7] = (_Float16)(x1.w * qscale);
                qf[rg][c] = hv;
            }
        }
    }

    floatx4 acc[2][4];
    float l_[2];
    #pragma unroll
    for (int rg = 0; rg < 2; ++rg) {
        #pragma unroll
        for (int nb = 0; nb < 4; ++nb) acc[rg][nb] = floatx4{0.f, 0.f, 0.f, 0.f};
        l_[rg] = 0.f;
    }

    const int i_lo = qblk * BQ + wq * 32;

    auto pack4 = [](const floatx4& v) -> half4 {   // 4 f32 -> half4 (RTZ)
        fp16x2 lo = __builtin_amdgcn_cvt_pkrtz(v[0], v[1]);
        fp16x2 hi = __builtin_amdgcn_cvt_pkrtz(v[2], v[3]);
        half4 w;
        w[0] = (_Float16)lo[0]; w[1] = (_Float16)lo[1];
        w[2] = (_Float16)hi[0]; w[3] = (_Float16)hi[1];
        return w;
    };

    // ---- gload_lds staging geometry.
    // Per-lane GLOBAL src; wave-uniform LDS dest (HW writes base + lane*16B).
    // K slice: wave w covers rows 8w..8w+7 of the [64][64] fp16 tile.
    // V slice: wave w covers dim-rows 8w..8w+7 of the [64][2048] fp16 tensor,
    //          64-key window per tile (contiguous 128B per row).
    const int lrow = lane >> 3;            // 0..7
    const int lchk = (lane & 7) << 3;      // elem 0,8,..,56
    const _Float16* ksrc = kbh + (wave * 8 + lrow) * D_ + lchk;          // +kt*4096
    const _Float16* vsrc = vbh + (size_t)(wave * 8 + lrow) * S_ + lchk;  // +kt*64
    const int dstoff = wave * 512;         // elems; wave-uniform

    auto issue = [&](int kt, int bufe) {
        __builtin_amdgcn_global_load_lds(
            (const __attribute__((address_space(1))) void*)(ksrc + (size_t)kt * 4096),
            (__attribute__((address_space(3))) void*)(KL + bufe + dstoff), 16, 0, 0);
        __builtin_amdgcn_global_load_lds(
            (const __attribute__((address_space(1))) void*)(vsrc + (size_t)kt * 64),
            (__attribute__((address_space(3))) void*)(VT + bufe + dstoff), 16, 0, 0);
    };

    issue(0, 0);
    __syncthreads();   // compiler drains vmcnt before the barrier -> buf0 ready

    for (int kt = 0; kt < ntiles; ++kt) {
        const int curb = (kt & 1) * 4096;
        if (kt + 1 < ntiles) issue(kt + 1, curb ^ 4096);  // async, drains at barrier

        const int keybase = kt * BK + kh * 32;

        // wave-uniform bias classification: fold uniform shift into C-init
        const bool unif_next = (i_lo + 31 <= keybase);
        const bool unif_far  = (i_lo >= keybase + 247);
        const float cinit = unif_next ? -sh_next : (unif_far ? -sh_far : 0.f);
        const floatx4 ci = {cinit, cinit, cinit, cinit};

        // ---- S^T = K (Q*log2e/8)^T : row=key (quad*4+r), col=qrow (t16)
        floatx4 sa[2][2];
        #pragma unroll
        for (int rg = 0; rg < 2; ++rg)
            #pragma unroll
            for (int nb = 0; nb < 2; ++nb) sa[rg][nb] = ci;
        __builtin_amdgcn_s_setprio(1);
        #pragma unroll
        for (int kc = 0; kc < 2; ++kc) {
            #pragma unroll
            for (int nb = 0; nb < 2; ++nb) {
                half8 af = *reinterpret_cast<const half8*>(
                    KL + curb + (kh * 32 + nb * 16 + t16) * LDSH + kc * 32 + quad * 8);
                sa[0][nb] = __builtin_amdgcn_mfma_f32_16x16x32_f16(af, qf[0][kc], sa[0][nb], 0, 0, 0);
                sa[1][nb] = __builtin_amdgcn_mfma_f32_16x16x32_f16(af, qf[1][kc], sa[1][nb], 0, 0, 0);
            }
        }
        __builtin_amdgcn_s_setprio(0);

        // V reads now: independent of sa, latency hides under exp2
        half4 bvv[4][2];
        #pragma unroll
        for (int nb = 0; nb < 4; ++nb) {
            #pragma unroll
            for (int s = 0; s < 2; ++s) {
                bvv[nb][s] = *reinterpret_cast<const half4*>(
                    VT + curb + (nb * 16 + t16) * LDSH + kh * 32 + s * 16 + quad * 4);
            }
        }

        // LUT bias only on the (few) diagonal tiles
        if (!unif_next && !unif_far) {
            #pragma unroll
            for (int rg = 0; rg < 2; ++rg) {
                const int d0 = i_lo + rg * 16 + t16 - keybase - quad * 4;
                #pragma unroll
                for (int nb = 0; nb < 2; ++nb) {
                    #pragma unroll
                    for (int r = 0; r < 4; ++r) {
                        int d = d0 - nb * 16 - r;
                        d = d < 0 ? 0 : (d > 255 ? 255 : d);
                        sa[rg][nb][r] += lut[d];
                    }
                }
            }
        }
        // key-padding mask on the boundary tile only
        if ((kt == ntiles - 1) && (len & 63)) {
            #pragma unroll
            for (int nb = 0; nb < 2; ++nb) {
                #pragma unroll
                for (int r = 0; r < 4; ++r) {
                    bool valid = (keybase + nb * 16 + quad * 4 + r) < len;
                    #pragma unroll
                    for (int rg = 0; rg < 2; ++rg)
                        sa[rg][nb][r] = valid ? sa[rg][nb][r] : -1e30f;
                }
            }
        }

        // fixed-shift softmax + partial l
        #pragma unroll
        for (int rg = 0; rg < 2; ++rg) {
            float ssum = 0.f;
            #pragma unroll
            for (int nb = 0; nb < 2; ++nb)
                #pragma unroll
                for (int r = 0; r < 4; ++r) {
                    sa[rg][nb][r] = EXP2F(sa[rg][nb][r]);
                    ssum += sa[rg][nb][r];
                }
            l_[rg] += ssum;
        }

        // O += P V, P in registers (16x16x16: A-operand = S^T C-layout)
        {
            half4 aA0 = pack4(sa[0][0]);
            half4 aB0 = pack4(sa[0][1]);
            half4 aA1 = pack4(sa[1][0]);
            half4 aB1 = pack4(sa[1][1]);
            __builtin_amdgcn_s_setprio(1);
            #pragma unroll
            for (int nb = 0; nb < 4; ++nb) {
                acc[0][nb] = __builtin_amdgcn_mfma_f32_16x16x16f16(aA0, bvv[nb][0], acc[0][nb], 0, 0, 0);
                acc[0][nb] = __builtin_amdgcn_mfma_f32_16x16x16f16(aB0, bvv[nb][1], acc[0][nb], 0, 0, 0);
                acc[1][nb] = __builtin_amdgcn_mfma_f32_16x16x16f16(aA1, bvv[nb][0], acc[1][nb], 0, 0, 0);
                acc[1][nb] = __builtin_amdgcn_mfma_f32_16x16x16f16(aB1, bvv[nb][1], acc[1][nb], 0, 0, 0);
            }
            __builtin_amdgcn_s_setprio(0);
        }

        __syncthreads();   // drains vmcnt (next tile landed) + lgkm; one barrier/tile
    }

    // ---- epilogue: combine kh-pair additive partials, normalize, store
    float lh[2];
    #pragma unroll
    for (int rg = 0; rg < 2; ++rg) {
        float lv = l_[rg];
        lv += __shfl_xor(lv, 16, 64);
        lv += __shfl_xor(lv, 32, 64);
        lh[rg] = lv;
    }
    float* Ox = reinterpret_cast<float*>(smem);           // [128][OX_STR]
    float* Lx = reinterpret_cast<float*>(smem + LX_OFF);  // [128]
    if (kh == 1) {
        #pragma unroll
        for (int rg = 0; rg < 2; ++rg) {
            #pragma unroll
            for (int nb = 0; nb < 4; ++nb)
                #pragma unroll
                for (int r = 0; r < 4; ++r)
                    Ox[(wq * 32 + rg * 16 + quad * 4 + r) * OX_STR + nb * 16 + t16] =
                        acc[rg][nb][r];
            if (quad == 0) Lx[wq * 32 + rg * 16 + t16] = lh[rg];
        }
    }
    __syncthreads();
    if (kh == 0) {
        #pragma unroll
        for (int rg = 0; rg < 2; ++rg) {
            const float inv = 1.f / (lh[rg] + Lx[wq * 32 + rg * 16 + t16]);
            #pragma unroll
            for (int r = 0; r < 4; ++r) {
                const int rowloc = quad * 4 + r;
                const float invr = __shfl(inv, (lane & 48) | rowloc, 64);
                const int row = qblk * BQ + wq * 32 + rg * 16 + rowloc;
                #pragma unroll
                for (int nb = 0; nb < 4; ++nb)
                    optr[(size_t)row * D_ + nb * 16 + t16] =
                        (acc[rg][nb][r] +
                         Ox[(wq * 32 + rg * 16 + rowloc) * OX_STR + nb * 16 + t16]) * invr;
            }
        }
    }
}
#endif  // HAS_GLDS

// ===========================================================================
// Fallback: the round-5 kernel (verified 49.7us) — used if ws too small or
// no gload_lds builtin. Reg-staged, XOR-swizzled LDS.
// ===========================================================================
__global__ __launch_bounds__(512, 4)
void t5_attn_fb(const float* __restrict__ qg_, const float* __restrict__ kg_,
                const float* __restrict__ vg_, const float* __restrict__ bt,
                const int* __restrict__ elen, float* __restrict__ outg_)
{
    __shared__ __align__(16) unsigned char smem[SMEM_BYTES];
    _Float16* KL = reinterpret_cast<_Float16*>(smem);
    _Float16* VT = reinterpret_cast<_Float16*>(smem + VT_OFF);
    float*   lut = reinterpret_cast<float*>(smem + LUT_OFF);

    const int tid  = threadIdx.x;
    const int wave = tid >> 6;
    const int lane = tid & 63;
    const int quad = lane >> 4;
    const int t16  = lane & 15;
    const int t8   = t16 & 7;
    const int wq   = wave >> 1;
    const int kh   = wave & 1;

    const int f    = blockIdx.x + NQB * (blockIdx.y + H_ * blockIdx.z);
    const int qblk = (f >> 3) & 15;
    const int bh   = (f & 7) | ((f >> 7) << 3);
    const int h    = bh & 15;
    const int b    = bh >> 4;

    if (tid < 256) {
        int n = tid;
        int bucket;
        if (n < 16) bucket = n;
        else {
            int vl = (int)(__log2f((float)n * 0.0625f) * 4.0f);
            bucket = 16 + (vl < 15 ? vl : 15);
        }
        lut[n] = bt[bucket * H_ + h] * LOG2E - FIXM;
    }
    const float sh_next = FIXM - bt[h] * LOG2E;
    const float sh_far  = FIXM - bt[31 * H_ + h] * LOG2E;

    const int len = (elen[1] == 0) ? elen[2 * b] : elen[b];
    const int ntiles = (len + BK - 1) >> 6;

    const size_t bhoff = ((size_t)b * H_ + h) * (size_t)(S_ * D_);
    const float* qptr = qg_ + bhoff;
    const float* kptr = kg_ + bhoff;
    const float* vptr = vg_ + bhoff;
    float*       optr = outg_ + bhoff;

    half8 qf[2][2];
    {
        const float qscale = 0.125f * LOG2E;
        #pragma unroll
        for (int rg = 0; rg < 2; ++rg) {
            const int row = qblk * BQ + wq * 32 + rg * 16 + t16;
            const float* qp = qptr + (size_t)row * D_ + quad * 8;
            #pragma unroll
            for (int c = 0; c < 2; ++c) {
                const float4* pq = reinterpret_cast<const float4*>(qp + c * 32);
                float4 x0 = pq[0], x1 = pq[1];
                half8 hv;
                hv[0] = (_Float16)(x0.x * qscale); hv[1] = (_Float16)(x0.y * qscale);
                hv[2] = (_Float16)(x0.z * qscale); hv[3] = (_Float16)(x0.w * qscale);
                hv[4] = (_Float16)(x1.x * qscale); hv[5] = (_Float16)(x1.y * qscale);
                hv[6] = (_Float16)(x1.z * qscale); hv[7] = (_Float16)(x1.w * qscale);
                qf[rg][c] = hv;
            }
        }
    }

    floatx4 acc[2][4];
    float l_[2];
    #pragma unroll
    for (int rg = 0; rg < 2; ++rg) {
        #pragma unroll
        for (int nb = 0; nb < 4; ++nb) acc[rg][nb] = floatx4{0.f, 0.f, 0.f, 0.f};
        l_[rg] = 0.f;
    }

    const int i_lo = qblk * BQ + wq * 32;

    auto pack4 = [](const floatx4& v) -> half4 {
        fp16x2 lo = __builtin_amdgcn_cvt_pkrtz(v[0], v[1]);
        fp16x2 hi = __builtin_amdgcn_cvt_pkrtz(v[2], v[3]);
        half4 w;
        w[0] = (_Float16)lo[0]; w[1] = (_Float16)lo[1];
        w[2] = (_Float16)hi[0]; w[3] = (_Float16)hi[1];
        return w;
    };

    const int krow = tid >> 3;
    const int kst  = krow * LDSH + (((tid & 7) ^ (krow & 7)) << 3);
    const int vst  = lane * LDSH + ((wave ^ (lane & 7)) << 3);
    const int c8w  = (tid & 7) << 3;

    float4 kx0, kx1;
    float  vx[8];
    auto prefetch = [&](int kt) {
        const int ktc = kt < NKT ? kt : NKT - 1;
        const float4* pp = reinterpret_cast<const float4*>(
            kptr + (size_t)(ktc * BK + krow) * D_ + c8w);
        kx0 = pp[0];
        kx1 = pp[1];
        const float* vb = vptr + (size_t)(ktc * BK + wave * 8) * D_ + lane;
        #pragma unroll
        for (int jj = 0; jj < 8; ++jj)
            vx[jj] = vb[jj * D_];
    };
    auto stage = [&](int bufe) {
        half8 hv;
        hv[0]=(_Float16)kx0.x; hv[1]=(_Float16)kx0.y; hv[2]=(_Float16)kx0.z; hv[3]=(_Float16)kx0.w;
        hv[4]=(_Float16)kx1.x; hv[5]=(_Float16)kx1.y; hv[6]=(_Float16)kx1.z; hv[7]=(_Float16)kx1.w;
        *reinterpret_cast<half8*>(KL + bufe + kst) = hv;
        half8 vv;
        #pragma unroll
        for (int jj = 0; jj < 8; ++jj) vv[jj] = (_Float16)vx[jj];
        *reinterpret_cast<half8*>(VT + bufe + vst) = vv;
    };

    prefetch(0);
    stage(0);
    __syncthreads();

    for (int kt = 0; kt < ntiles; ++kt) {
        const int curb = (kt & 1) * 4096;
        const bool more = (kt + 1) < ntiles;
        if (more) prefetch(kt + 1);

        const int keybase = kt * BK + kh * 32;
        const bool unif_next = (i_lo + 31 <= keybase);
        const bool unif_far  = (i_lo >= keybase + 247);
        const float cinit = unif_next ? -sh_next : (unif_far ? -sh_far : 0.f);
        const floatx4 ci = {cinit, cinit, cinit, cinit};

        floatx4 sa[2][2];
        #pragma unroll
        for (int rg = 0; rg < 2; ++rg)
            #pragma unroll
            for (int nb = 0; nb < 2; ++nb) sa[rg][nb] = ci;
        __builtin_amdgcn_s_setprio(1);
        #pragma unroll
        for (int kc = 0; kc < 2; ++kc) {
            #pragma unroll
            for (int nb = 0; nb < 2; ++nb) {
                half8 af = *reinterpret_cast<const half8*>(
                    KL + curb + (kh * 32 + nb * 16 + t16) * LDSH +
                    ((((kc << 2) | quad) ^ t8) << 3));
                sa[0][nb] = __builtin_amdgcn_mfma_f32_16x16x32_f16(af, qf[0][kc], sa[0][nb], 0, 0, 0);
                sa[1][nb] = __builtin_amdgcn_mfma_f32_16x16x32_f16(af, qf[1][kc], sa[1][nb], 0, 0, 0);
            }
        }
        __builtin_amdgcn_s_setprio(0);

        half4 bvv[4][2];
        #pragma unroll
        for (int nb = 0; nb < 4; ++nb) {
            #pragma unroll
            for (int s = 0; s < 2; ++s) {
                bvv[nb][s] = *reinterpret_cast<const half4*>(
                    VT + curb + (nb * 16 + t16) * LDSH +
                    ((((kh << 2) | (s << 1) | (quad >> 1)) ^ t8) << 3) +
                    ((quad & 1) << 2));
            }
        }

        if (!unif_next && !unif_far) {
            #pragma unroll
            for (int rg = 0; rg < 2; ++rg) {
                const int d0 = i_lo + rg * 16 + t16 - keybase - quad * 4;
                #pragma unroll
                for (int nb = 0; nb < 2; ++nb) {
                    #pragma unroll
                    for (int r = 0; r < 4; ++r) {
                        int d = d0 - nb * 16 - r;
                        d = d < 0 ? 0 : (d > 255 ? 255 : d);
                        sa[rg][nb][r] += lut[d];
                    }
                }
            }
        }
        if ((kt == ntiles - 1) && (len & 63)) {
            #pragma unroll
            for (int nb = 0; nb < 2; ++nb) {
                #pragma unroll
                for (int r = 0; r < 4; ++r) {
                    bool valid = (keybase + nb * 16 + quad * 4 + r) < len;
                    #pragma unroll
                    for (int rg = 0; rg < 2; ++rg)
                        sa[rg][nb][r] = valid ? sa[rg][nb][r] : -1e30f;
                }
            }
        }

        #pragma unroll
        for (int rg = 0; rg < 2; ++rg) {
            float ssum = 0.f;
            #pragma unroll
            for (int nb = 0; nb < 2; ++nb)
                #pragma unroll
                for (int r = 0; r < 4; ++r) {
                    sa[rg][nb][r] = EXP2F(sa[rg][nb][r]);
                    ssum += sa[rg][nb][r];
                }
            l_[rg] += ssum;
        }

        {
            half4 aA0 = pack4(sa[0][0]);
            half4 aB0 = pack4(sa[0][1]);
            half4 aA1 = pack4(sa[1][0]);
            half4 aB1 = pack4(sa[1][1]);
            __builtin_amdgcn_s_setprio(1);
            #pragma unroll
            for (int nb = 0; nb < 4; ++nb) {
                acc[0][nb] = __builtin_amdgcn_mfma_f32_16x16x16f16(aA0, bvv[nb][0], acc[0][nb], 0, 0, 0);
                acc[0][nb] = __builtin_amdgcn_mfma_f32_16x16x16f16(aB0, bvv[nb][1], acc[0][nb], 0, 0, 0);
                acc[1][nb] = __builtin_amdgcn_mfma_f32_16x16x16f16(aA1, bvv[nb][0], acc[1][nb], 0, 0, 0);
                acc[1][nb] = __builtin_amdgcn_mfma_f32_16x16x16f16(aB1, bvv[nb][1], acc[1][nb], 0, 0, 0);
            }
            __builtin_amdgcn_s_setprio(0);
        }

        if (more) stage(curb ^ 4096);
        __syncthreads();
    }

    float lh[2];
    #pragma unroll
    for (int rg = 0; rg < 2; ++rg) {
        float lv = l_[rg];
        lv += __shfl_xor(lv, 16, 64);
        lv += __shfl_xor(lv, 32, 64);
        lh[rg] = lv;
    }
    float* Ox = reinterpret_cast<float*>(smem);
    float* Lx = reinterpret_cast<float*>(smem + LX_OFF);
    if (kh == 1) {
        #pragma unroll
        for (int rg = 0; rg < 2; ++rg) {
            #pragma unroll
            for (int nb = 0; nb < 4; ++nb)
                #pragma unroll
                for (int r = 0; r < 4; ++r)
                    Ox[(wq * 32 + rg * 16 + quad * 4 + r) * OX_STR + nb * 16 + t16] =
                        acc[rg][nb][r];
            if (quad == 0) Lx[wq * 32 + rg * 16 + t16] = lh[rg];
        }
    }
    __syncthreads();
    if (kh == 0) {
        #pragma unroll
        for (int rg = 0; rg < 2; ++rg) {
            const float inv = 1.f / (lh[rg] + Lx[wq * 32 + rg * 16 + t16]);
            #pragma unroll
            for (int r = 0; r < 4; ++r) {
                const int rowloc = quad * 4 + r;
                const float invr = __shfl(inv, (lane & 48) | rowloc, 64);
                const int row = qblk * BQ + wq * 32 + rg * 16 + rowloc;
                #pragma unroll
                for (int nb = 0; nb < 4; ++nb)
                    optr[(size_t)row * D_ + nb * 16 + t16] =
                        (acc[rg][nb][r] +
                         Ox[(wq * 32 + rg * 16 + rowloc) * OX_STR + nb * 16 + t16]) * invr;
            }
        }
    }
}

extern "C" void kernel_launch(void* const* d_in, const int* in_sizes, int n_in,
                              void* d_out, int out_size, void* d_ws, size_t ws_size,
                              hipStream_t stream) {
    const float* q  = (const float*)d_in[0];
    const float* k  = (const float*)d_in[1];
    const float* v  = (const float*)d_in[2];
    const float* bt = (const float*)d_in[3];
    const int*   el = (const int*)d_in[4];
    float* out = (float*)d_out;
#if HAS_GLDS
    if (d_ws != nullptr && ws_size >= WS_NEED) {
        _Float16* kws = (_Float16*)d_ws;
        _Float16* vws = kws + KV_ELEMS;
        t5_prep<<<dim3(2048), 256, 0, stream>>>(k, v, kws, vws);
        t5_attn_g<<<dim3(NQB, H_, B_), 512, 0, stream>>>(q, kws, vws, bt, el, out);
        return;
    }
#endif
    t5_attn_fb<<<dim3(NQB, H_, B_), 512, 0, stream>>>(q, k, v, bt, el, out);
}